// Round 8
// baseline (243.748 us; speedup 1.0000x reference)
//
#include <hip/hip_runtime.h>
#include <cmath>

#define B_ 2
#define S_ 2048
#define D_ 1024
#define H_ 16
#define HD_ 64
#define M_ 4096   // B*S

typedef __attribute__((ext_vector_type(8))) short short8;
typedef __attribute__((ext_vector_type(4))) short short4v;
typedef __attribute__((ext_vector_type(4))) float f32x4;

// round-to-nearest-even f32 -> bf16 (values finite here)
__device__ __forceinline__ short f2bf(float x) {
    unsigned u = __builtin_bit_cast(unsigned, x);
    u += 0x7fffu + ((u >> 16) & 1u);
    return (short)(u >> 16);
}

__device__ __forceinline__ void gload_lds16(const short* g, short* l) {
    __builtin_amdgcn_global_load_lds(
        (const __attribute__((address_space(1))) unsigned int*)g,
        (__attribute__((address_space(3))) unsigned int*)l, 16, 0, 0);
}

// counted vmcnt wait — prefetches stay in flight across barriers
template<int N> __device__ __forceinline__ void vwait() {
    if constexpr (N == 0) asm volatile("s_waitcnt vmcnt(0)" ::: "memory");
    else if constexpr (N == 2) asm volatile("s_waitcnt vmcnt(2)" ::: "memory");
    else if constexpr (N == 4) asm volatile("s_waitcnt vmcnt(4)" ::: "memory");
}
__device__ __forceinline__ void bar() { __builtin_amdgcn_s_barrier(); }

// ---------------------------------------------------------------------------
// cast fp32 inputs to bf16
__global__ __launch_bounds__(256) void cast_all_kernel(
    const float* __restrict__ x,  const float* __restrict__ Wq,
    const float* __restrict__ Wk, const float* __restrict__ Wv,
    const float* __restrict__ Wo,
    short* __restrict__ xb, short* __restrict__ Wqkvb, short* __restrict__ Wob)
{
    const size_t i = (size_t)blockIdx.x * 256 + threadIdx.x;  // float4 index
    const float* src; short* dst; size_t off;
    if (i < 1048576)      { src = x;  dst = xb;              off = i; }
    else if (i < 1310720) { src = Wq; dst = Wqkvb;           off = i - 1048576; }
    else if (i < 1572864) { src = Wk; dst = Wqkvb + 1048576; off = i - 1310720; }
    else if (i < 1835008) { src = Wv; dst = Wqkvb + 2097152; off = i - 1572864; }
    else                  { src = Wo; dst = Wob;             off = i - 1835008; }
    float4 v = ((const float4*)src)[off];
    short4v o = { f2bf(v.x), f2bf(v.y), f2bf(v.z), f2bf(v.w) };
    ((short4v*)dst)[off] = o;
}

// ---------------------------------------------------------------------------
// Stage-ahead-2 MFMA GEMM, ONE barrier per chunk: C = A @ W^T (+bias). BK=32.
// 3 static buffers; per chunk: vwait<LPC> -> s_barrier -> STAGE(c+2) ->
// COMP(c). STAGE(c+2) writes buffer (c+2)%3 = (c-1)%3, last read during
// COMP(c-1) which all waves finished before this chunk's bar; vwait<LPC>
// before the bar means every wave's chunk-c loads landed, so after the bar
// chunk c is complete in LDS. Halves barrier count vs d3 (32 vs 64) and
// removes all lgkm drains; loads get ~2 chunk-periods of cover.
// LDS rows 32 shorts (64B); 16B slot s of row r holds data slot s^((r>>1)&3)
// (pre-swizzled GLOBAL source, linear LDS dest; same XOR on b128 reads ->
// worst 2-way bank aliasing = free; 0 conflicts measured 4 rounds).
// 4 waves in 2x2; wave tile (TM/2)x(TN/2).
// QKV: 128x128 -> 48 KB LDS -> 3 blocks/CU, grid (24,32) = 1 generation.
// proj: 64x64 -> 24 KB LDS, grid (16,64).
// MODE 0: fp32 out [M,1024] + bias
// MODE 1: fused QKV epilogue (q,k: bias+RoPE -> [BH,S,HD]; v: bias -> [BH,HD,S])
template<int MODE, int TM, int TN>
__global__ __launch_bounds__(256) void gemm_sa2(
    const short* __restrict__ A, const short* __restrict__ Bw,
    const float* __restrict__ b0p, const float* __restrict__ b1p, const float* __restrict__ b2p,
    const float* __restrict__ freqs,
    void* __restrict__ out0, void* __restrict__ out1, void* __restrict__ out2)
{
    constexpr int RT = TM / 32, CT = TN / 32;   // per-wave mfma tiles
    constexpr int LPC = TM/64 + TN/64;          // gloads per chunk per wave
    __shared__ __align__(16) short A0[TM*32];
    __shared__ __align__(16) short A1[TM*32];
    __shared__ __align__(16) short A2[TM*32];
    __shared__ __align__(16) short B0[TN*32];
    __shared__ __align__(16) short B1[TN*32];
    __shared__ __align__(16) short B2[TN*32];
    const int t = threadIdx.x;
    const int w = t >> 6;
    const int lane = t & 63;
    const int qd = lane >> 4, l = lane & 15;
    const int n0 = blockIdx.x * TN, m0 = blockIdx.y * TM;
    const int wr = (w >> 1) * (TM/2), wc = (w & 1) * (TN/2);
    // staging: one gload call stages 16 rows x 64B; lane -> row lane>>2, slot lane&3
    const int srow  = lane >> 2;                             // 0..15
    const int sslot = ((lane & 3) ^ ((lane >> 3) & 3)) * 8;  // pre-swizzled src col (shorts)
    // read: data slot qd of row R lives at LDS slot qd ^ ((R>>1)&3) = qd ^ ((l>>1)&3)
    const int rsw = (l >> 1) & 3;

    f32x4 acc[RT][CT] = {};

    auto STAGE = [&](int c, short* As, short* Bss) {
        const int k0 = c * 32;
        #pragma unroll
        for (int j = 0; j < TM/64; ++j) {
            const int r0 = (j*4 + w) * 16;
            gload_lds16(A + (size_t)(m0 + r0 + srow)*1024 + k0 + sslot, &As[r0*32]);
        }
        #pragma unroll
        for (int j = 0; j < TN/64; ++j) {
            const int r0 = (j*4 + w) * 16;
            gload_lds16(Bw + (size_t)(n0 + r0 + srow)*1024 + k0 + sslot, &Bss[r0*32]);
        }
    };

    auto COMP = [&](const short* As, const short* Bss) {
        short8 af[RT], bfr[CT];
        #pragma unroll
        for (int rt = 0; rt < RT; ++rt)
            af[rt] = *(const short8*)&As[(wr + rt*16 + l)*32 + ((qd ^ rsw) << 3)];
        #pragma unroll
        for (int ct = 0; ct < CT; ++ct)
            bfr[ct] = *(const short8*)&Bss[(wc + ct*16 + l)*32 + ((qd ^ rsw) << 3)];
        #pragma unroll
        for (int rt = 0; rt < RT; ++rt)
            #pragma unroll
            for (int ct = 0; ct < CT; ++ct)
                acc[rt][ct] = __builtin_amdgcn_mfma_f32_16x16x32_bf16(af[rt], bfr[ct], acc[rt][ct], 0, 0, 0);
    };

    // 32 chunks of K=32; chunk c uses buffer c%3; stage-ahead-2.
    STAGE(0, A0, B0);
    STAGE(1, A1, B1);
    for (int p = 0; p <= 27; p += 3) {      // chunks p..p+2 (0..29); stages p+2..p+4 (2..31)
        vwait<LPC>(); bar();                // chunk p landed everywhere (p+1 in flight)
        STAGE(p + 2, A2, B2);
        COMP(A0, B0);
        vwait<LPC>(); bar();
        STAGE(p + 3, A0, B0);
        COMP(A1, B1);
        vwait<LPC>(); bar();
        STAGE(p + 4, A1, B1);
        COMP(A2, B2);
    }
    vwait<LPC>(); bar();
    COMP(A0, B0);                           // chunk 30 (30%3 == 0)
    vwait<0>(); bar();
    COMP(A1, B1);                           // chunk 31 (31%3 == 1)

    if (MODE == 0) {
        float* out = (float*)out0;
        #pragma unroll
        for (int rt = 0; rt < RT; ++rt)
            #pragma unroll
            for (int ct = 0; ct < CT; ++ct) {
                const int n = n0 + wc + ct*16 + l;
                const float bias = b0p[n];
                #pragma unroll
                for (int r = 0; r < 4; ++r) {
                    const int m = m0 + wr + rt*16 + qd*4 + r;
                    out[(size_t)m*1024 + n] = acc[rt][ct][r] + bias;
                }
            }
    } else {
        const int sel = n0 >> 10;          // 0=q 1=k 2=v (uniform per block)
        const int nb = n0 & 1023;
        const float* bias = (sel == 0) ? b0p : (sel == 1) ? b1p : b2p;
        if (sel < 2) {
            short* outg = (short*)((sel == 0) ? out0 : out1);
            #pragma unroll
            for (int rt = 0; rt < RT; ++rt)
                #pragma unroll
                for (int ct = 0; ct < CT; ++ct) {
                    const int d = nb + wc + ct*16 + l;
                    const float bsv = bias[d];
                    const int h = d >> 6, hd = d & 63;
                    #pragma unroll
                    for (int r = 0; r < 4; ++r) {
                        const int m = m0 + wr + rt*16 + qd*4 + r;
                        const int bb = m >> 11, s = m & 2047;
                        float val = acc[rt][ct][r] + bsv;
                        float pv = __shfl_xor(val, 1);
                        const float* f = freqs + (size_t)s*128 + (size_t)(hd >> 1)*4;
                        float o = (d & 1) ? (f[2]*pv + f[3]*val) : (f[0]*val + f[1]*pv);
                        outg[((size_t)(bb*16 + h)*2048 + s)*64 + hd] = f2bf(o);
                    }
                }
        } else {
            short* outv = (short*)out2;
            #pragma unroll
            for (int rt = 0; rt < RT; ++rt)
                #pragma unroll
                for (int ct = 0; ct < CT; ++ct) {
                    const int d = nb + wc + ct*16 + l;
                    const float bsv = bias[d];
                    const int h = d >> 6, hd = d & 63;
                    const int m0r = m0 + wr + rt*16 + qd*4;
                    const int bb = m0r >> 11, s0 = m0r & 2047;
                    short4v pk;
                    #pragma unroll
                    for (int r = 0; r < 4; ++r) pk[r] = f2bf(acc[rt][ct][r] + bsv);
                    *(short4v*)&outv[((size_t)(bb*16 + h)*64 + hd)*2048 + s0] = pk;  // v^T
                }
        }
    }
}

// ---------------------------------------------------------------------------
// MFMA flash attention — R4 version (best-measured), kept verbatim:
// 8 waves x 16 queries (512 threads), STATIC double-buffers (K0/K1/V0/V1,
// pair-unrolled), prefetch issued before compute, ONE __syncthreads per
// K-tile. K/V^T staged via global_load_lds with PRE-SWIZZLED global source
// (16B slot s of row r holds slot s^(r&7), 128B rows); all b128 reads apply
// the same XOR -> conflict-free. P in a separate buffer (wave-local rows).
__global__ __launch_bounds__(512) void attn_mfma(
    const short* __restrict__ qg, const short* __restrict__ kg,
    const short* __restrict__ vtg, short* __restrict__ og)
{
    __shared__ __align__(16) short K0[64*64];
    __shared__ __align__(16) short K1[64*64];
    __shared__ __align__(16) short V0[64*64];
    __shared__ __align__(16) short V1[64*64];
    __shared__ __align__(16) short Pb[128*64];

    const int t = threadIdx.x;
    const int w = t >> 6;                  // 0..7
    const int lane = t & 63;
    const int qd = lane >> 4, l = lane & 15;
    const int l7 = lane & 7;
    const int q0 = blockIdx.x * 128;
    const int bh = blockIdx.y;

    // staging coords: each wave stages 8 rows/call; lane -> (row rl, slot)
    const int rl  = lane >> 3;                 // 0..7
    const int ss8 = ((lane & 7) ^ rl) << 3;    // pre-swizzled source slot (shorts)

    short8 qf[2];
    const short* qb = qg + ((size_t)bh*2048 + q0 + w*16)*64;
    #pragma unroll
    for (int kf = 0; kf < 2; ++kf)
        qf[kf] = *(const short8*)&qb[l*64 + kf*32 + qd*8];

    f32x4 oacc[4] = {};
    float lsum = 0.f;

    const short* kbase = kg  + (size_t)bh*2048*64;
    const short* vbase = vtg + (size_t)bh*64*2048;
    const float SC = 0.125f * 1.44269504088896340736f;

    auto PREF = [&](int c, short* Kd, short* Vd) {
        gload_lds16(kbase + (size_t)(c*64 + w*8 + rl)*64 + ss8,   &Kd[(w*8)*64]);
        gload_lds16(vbase + (size_t)(w*8 + rl)*2048 + c*64 + ss8, &Vd[(w*8)*64]);
    };

    auto TILE = [&](const short* Kc, const short* Vc) {
        // S^T = K @ Q^T  (64 keys x 16 q per wave)
        f32x4 sacc[4] = {};
        #pragma unroll
        for (int ct = 0; ct < 4; ++ct) {
            short8 k0f = *(const short8*)&Kc[(ct*16 + l)*64 + (((0 + qd) ^ l7) << 3)];
            short8 k1f = *(const short8*)&Kc[(ct*16 + l)*64 + (((4 + qd) ^ l7) << 3)];
            sacc[ct] = __builtin_amdgcn_mfma_f32_16x16x32_bf16(k0f, qf[0], sacc[ct], 0, 0, 0);
            sacc[ct] = __builtin_amdgcn_mfma_f32_16x16x32_bf16(k1f, qf[1], sacc[ct], 0, 0, 0);
        }
        // softmax numerator -> P (bf16), wave-local rows, swizzled b64 writes
        #pragma unroll
        for (int ct = 0; ct < 4; ++ct) {
            float p0 = exp2f(sacc[ct][0] * SC);
            float p1 = exp2f(sacc[ct][1] * SC);
            float p2 = exp2f(sacc[ct][2] * SC);
            float p3 = exp2f(sacc[ct][3] * SC);
            lsum += (p0 + p1) + (p2 + p3);
            union { unsigned u[2]; short4v s; } cv;
            asm("v_cvt_pk_bf16_f32 %0, %1, %2" : "=v"(cv.u[0]) : "v"(p0), "v"(p1));
            asm("v_cvt_pk_bf16_f32 %0, %1, %2" : "=v"(cv.u[1]) : "v"(p2), "v"(p3));
            *(short4v*)&Pb[(w*16 + l)*64 + (((ct*32 + qd*8) ^ (l7 << 4)) >> 1)] = cv.s;
        }
        // O += P @ V   (P rows are this wave's -> LDS in-order, no barrier)
        #pragma unroll
        for (int kf = 0; kf < 2; ++kf) {
            const int so = ((kf*4 + qd) ^ l7) << 3;
            short8 pa = *(const short8*)&Pb[(w*16 + l)*64 + so];
            #pragma unroll
            for (int ht = 0; ht < 4; ++ht) {
                short8 vb = *(const short8*)&Vc[(ht*16 + l)*64 + so];
                oacc[ht] = __builtin_amdgcn_mfma_f32_16x16x32_bf16(pa, vb, oacc[ht], 0, 0, 0);
            }
        }
    };

    // 32 K-tiles, pair-unrolled for compile-time buffer selection
    PREF(0, K0, V0);
    __syncthreads();
    for (int p = 0; p < 16; ++p) {
        PREF(2*p + 1, K1, V1);     // overlaps TILE below
        TILE(K0, V0);
        __syncthreads();           // drains prefetch; fences K0/V0 reuse
        if (p < 15)
            PREF(2*p + 2, K0, V0);
        TILE(K1, V1);
        __syncthreads();
    }

    lsum += __shfl_xor(lsum, 16);
    lsum += __shfl_xor(lsum, 32);
    float inv[4];
    #pragma unroll
    for (int r = 0; r < 4; ++r)
        inv[r] = 1.0f / __shfl(lsum, qd*4 + r);

    const int bb = bh >> 4, h = bh & 15;
    #pragma unroll
    for (int ht = 0; ht < 4; ++ht)
        #pragma unroll
        for (int r = 0; r < 4; ++r) {
            const int s = q0 + w*16 + qd*4 + r;
            og[((size_t)bb*2048 + s)*1024 + h*64 + ht*16 + l] =
                f2bf(oacc[ht][r] * inv[r]);
        }
}

// ---------------------------------------------------------------------------
extern "C" void kernel_launch(void* const* d_in, const int* in_sizes, int n_in,
                              void* d_out, int out_size, void* d_ws, size_t ws_size,
                              hipStream_t stream)
{
    const float* x  = (const float*)d_in[0];
    const float* fr = (const float*)d_in[1];
    const float* Wq = (const float*)d_in[2];
    const float* bq = (const float*)d_in[3];
    const float* Wk = (const float*)d_in[4];
    const float* bk = (const float*)d_in[5];
    const float* Wv = (const float*)d_in[6];
    const float* bv = (const float*)d_in[7];
    const float* Wo = (const float*)d_in[8];
    const float* bo = (const float*)d_in[9];
    float* out = (float*)d_out;

    short* ws    = (short*)d_ws;
    short* xb    = ws;                  // 4,194,304
    short* Wqkvb = xb    + 4194304;     // 3,145,728
    short* Wob   = Wqkvb + 3145728;     // 1,048,576
    short* qg    = Wob   + 1048576;     // [BH,S,HD]
    short* kg    = qg    + 4194304;     // [BH,S,HD]
    short* vtg   = kg    + 4194304;     // [BH,HD,S]
    short* og    = vtg   + 4194304;     // [B,S,H*HD]

    cast_all_kernel<<<8192, 256, 0, stream>>>(x, Wq, Wk, Wv, Wo, xb, Wqkvb, Wob);
    gemm_sa2<1,128,128><<<dim3(24, 32), 256, 0, stream>>>(xb, Wqkvb, bq, bk, bv, fr, qg, kg, vtg);
    attn_mfma<<<dim3(16, 32), 512, 0, stream>>>(qg, kg, vtg, og);
    gemm_sa2<0,64,64><<<dim3(16, 64), 256, 0, stream>>>(og, Wob, bo, nullptr, nullptr, nullptr,
                                                        out, nullptr, nullptr);
}

// Round 9
// 239.081 us; speedup vs baseline: 1.0195x; 1.0195x over previous
//
#include <hip/hip_runtime.h>
#include <cmath>

#define B_ 2
#define S_ 2048
#define D_ 1024
#define H_ 16
#define HD_ 64
#define M_ 4096   // B*S

typedef __attribute__((ext_vector_type(8))) short short8;
typedef __attribute__((ext_vector_type(4))) short short4v;
typedef __attribute__((ext_vector_type(4))) float f32x4;

// round-to-nearest-even f32 -> bf16 (values finite here)
__device__ __forceinline__ short f2bf(float x) {
    unsigned u = __builtin_bit_cast(unsigned, x);
    u += 0x7fffu + ((u >> 16) & 1u);
    return (short)(u >> 16);
}

__device__ __forceinline__ void gload_lds16(const short* g, short* l) {
    __builtin_amdgcn_global_load_lds(
        (const __attribute__((address_space(1))) unsigned int*)g,
        (__attribute__((address_space(3))) unsigned int*)l, 16, 0, 0);
}

// counted vmcnt wait — prefetches stay in flight across barriers
template<int N> __device__ __forceinline__ void vwait() {
    if constexpr (N == 0) asm volatile("s_waitcnt vmcnt(0)" ::: "memory");
    else if constexpr (N == 2) asm volatile("s_waitcnt vmcnt(2)" ::: "memory");
    else if constexpr (N == 3) asm volatile("s_waitcnt vmcnt(3)" ::: "memory");
    else if constexpr (N == 4) asm volatile("s_waitcnt vmcnt(4)" ::: "memory");
}
__device__ __forceinline__ void bar() { __builtin_amdgcn_s_barrier(); }

// ---------------------------------------------------------------------------
// cast fp32 inputs to bf16
__global__ __launch_bounds__(256) void cast_all_kernel(
    const float* __restrict__ x,  const float* __restrict__ Wq,
    const float* __restrict__ Wk, const float* __restrict__ Wv,
    const float* __restrict__ Wo,
    short* __restrict__ xb, short* __restrict__ Wqkvb, short* __restrict__ Wob)
{
    const size_t i = (size_t)blockIdx.x * 256 + threadIdx.x;  // float4 index
    const float* src; short* dst; size_t off;
    if (i < 1048576)      { src = x;  dst = xb;              off = i; }
    else if (i < 1310720) { src = Wq; dst = Wqkvb;           off = i - 1048576; }
    else if (i < 1572864) { src = Wk; dst = Wqkvb + 1048576; off = i - 1310720; }
    else if (i < 1835008) { src = Wv; dst = Wqkvb + 2097152; off = i - 1572864; }
    else                  { src = Wo; dst = Wob;             off = i - 1835008; }
    float4 v = ((const float4*)src)[off];
    short4v o = { f2bf(v.x), f2bf(v.y), f2bf(v.z), f2bf(v.w) };
    ((short4v*)dst)[off] = o;
}

// ---------------------------------------------------------------------------
// Stage-ahead-2 MFMA GEMM, ONE barrier per chunk: C = A @ W^T (+bias). BK=32.
// 3 static buffers; per chunk: vwait<LPC> -> s_barrier -> STAGE(c+2) ->
// COMP(c). Every wave vwaits BEFORE the barrier, so after it all waves'
// chunk-c loads are in LDS; STAGE(c+2) overwrites buffer (c-1)%3, which all
// waves finished reading before this barrier. Loads get ~2 chunk-periods of
// cover; vmcnt never drains to 0 in the main loop.
// LDS rows 32 shorts (64B); 16B slot s of row r holds data slot s^((r>>1)&3)
// (pre-swizzled GLOBAL source, linear LDS dest; same XOR on b128 reads ->
// worst 2-way bank aliasing = free; 0 conflicts measured 5 rounds).
// 4 waves in 2x2; wave tile (TM/2)x(TN/2).
// QKV: 128x128 -> 48 KB LDS -> 3 blocks/CU, grid (24,32) all-resident.
// proj: 128x64 -> 36 KB LDS -> 4 blocks/CU, grid (16,32) all-resident.
// MODE 0: fp32 out [M,1024] + bias
// MODE 1: fused QKV epilogue (q,k: bias+RoPE -> [BH,S,HD]; v: bias -> [BH,HD,S])
template<int MODE, int TM, int TN>
__global__ __launch_bounds__(256) void gemm_sa2(
    const short* __restrict__ A, const short* __restrict__ Bw,
    const float* __restrict__ b0p, const float* __restrict__ b1p, const float* __restrict__ b2p,
    const float* __restrict__ freqs,
    void* __restrict__ out0, void* __restrict__ out1, void* __restrict__ out2)
{
    constexpr int RT = TM / 32, CT = TN / 32;   // per-wave mfma tiles
    constexpr int LPC = TM/64 + TN/64;          // gloads per chunk per wave
    __shared__ __align__(16) short A0[TM*32];
    __shared__ __align__(16) short A1[TM*32];
    __shared__ __align__(16) short A2[TM*32];
    __shared__ __align__(16) short B0[TN*32];
    __shared__ __align__(16) short B1[TN*32];
    __shared__ __align__(16) short B2[TN*32];
    const int t = threadIdx.x;
    const int w = t >> 6;
    const int lane = t & 63;
    const int qd = lane >> 4, l = lane & 15;
    const int n0 = blockIdx.x * TN, m0 = blockIdx.y * TM;
    const int wr = (w >> 1) * (TM/2), wc = (w & 1) * (TN/2);
    // staging: one gload call stages 16 rows x 64B; lane -> row lane>>2, slot lane&3
    const int srow  = lane >> 2;                             // 0..15
    const int sslot = ((lane & 3) ^ ((lane >> 3) & 3)) * 8;  // pre-swizzled src col (shorts)
    // read: data slot qd of row R lives at LDS slot qd ^ ((R>>1)&3) = qd ^ ((l>>1)&3)
    const int rsw = (l >> 1) & 3;

    f32x4 acc[RT][CT] = {};

    auto STAGE = [&](int c, short* As, short* Bss) {
        const int k0 = c * 32;
        #pragma unroll
        for (int j = 0; j < TM/64; ++j) {
            const int r0 = (j*4 + w) * 16;
            gload_lds16(A + (size_t)(m0 + r0 + srow)*1024 + k0 + sslot, &As[r0*32]);
        }
        #pragma unroll
        for (int j = 0; j < TN/64; ++j) {
            const int r0 = (j*4 + w) * 16;
            gload_lds16(Bw + (size_t)(n0 + r0 + srow)*1024 + k0 + sslot, &Bss[r0*32]);
        }
    };

    auto COMP = [&](const short* As, const short* Bss) {
        short8 af[RT], bfr[CT];
        #pragma unroll
        for (int rt = 0; rt < RT; ++rt)
            af[rt] = *(const short8*)&As[(wr + rt*16 + l)*32 + ((qd ^ rsw) << 3)];
        #pragma unroll
        for (int ct = 0; ct < CT; ++ct)
            bfr[ct] = *(const short8*)&Bss[(wc + ct*16 + l)*32 + ((qd ^ rsw) << 3)];
        #pragma unroll
        for (int rt = 0; rt < RT; ++rt)
            #pragma unroll
            for (int ct = 0; ct < CT; ++ct)
                acc[rt][ct] = __builtin_amdgcn_mfma_f32_16x16x32_bf16(af[rt], bfr[ct], acc[rt][ct], 0, 0, 0);
    };

    // 32 chunks of K=32; chunk c uses buffer c%3; stage-ahead-2.
    STAGE(0, A0, B0);
    STAGE(1, A1, B1);
    for (int p = 0; p <= 27; p += 3) {      // chunks p..p+2 (0..29); stages p+2..p+4 (2..31)
        vwait<LPC>(); bar();                // chunk p landed everywhere (p+1 in flight)
        STAGE(p + 2, A2, B2);
        COMP(A0, B0);
        vwait<LPC>(); bar();
        STAGE(p + 3, A0, B0);
        COMP(A1, B1);
        vwait<LPC>(); bar();
        STAGE(p + 4, A1, B1);
        COMP(A2, B2);
    }
    vwait<LPC>(); bar();
    COMP(A0, B0);                           // chunk 30 (30%3 == 0)
    vwait<0>(); bar();
    COMP(A1, B1);                           // chunk 31 (31%3 == 1)

    if (MODE == 0) {
        float* out = (float*)out0;
        #pragma unroll
        for (int rt = 0; rt < RT; ++rt)
            #pragma unroll
            for (int ct = 0; ct < CT; ++ct) {
                const int n = n0 + wc + ct*16 + l;
                const float bias = b0p[n];
                #pragma unroll
                for (int r = 0; r < 4; ++r) {
                    const int m = m0 + wr + rt*16 + qd*4 + r;
                    out[(size_t)m*1024 + n] = acc[rt][ct][r] + bias;
                }
            }
    } else {
        const int sel = n0 >> 10;          // 0=q 1=k 2=v (uniform per block)
        const int nb = n0 & 1023;
        const float* bias = (sel == 0) ? b0p : (sel == 1) ? b1p : b2p;
        if (sel < 2) {
            short* outg = (short*)((sel == 0) ? out0 : out1);
            #pragma unroll
            for (int rt = 0; rt < RT; ++rt)
                #pragma unroll
                for (int ct = 0; ct < CT; ++ct) {
                    const int d = nb + wc + ct*16 + l;
                    const float bsv = bias[d];
                    const int h = d >> 6, hd = d & 63;
                    #pragma unroll
                    for (int r = 0; r < 4; ++r) {
                        const int m = m0 + wr + rt*16 + qd*4 + r;
                        const int bb = m >> 11, s = m & 2047;
                        float val = acc[rt][ct][r] + bsv;
                        float pv = __shfl_xor(val, 1);
                        const float* f = freqs + (size_t)s*128 + (size_t)(hd >> 1)*4;
                        float o = (d & 1) ? (f[2]*pv + f[3]*val) : (f[0]*val + f[1]*pv);
                        outg[((size_t)(bb*16 + h)*2048 + s)*64 + hd] = f2bf(o);
                    }
                }
        } else {
            short* outv = (short*)out2;
            #pragma unroll
            for (int rt = 0; rt < RT; ++rt)
                #pragma unroll
                for (int ct = 0; ct < CT; ++ct) {
                    const int d = nb + wc + ct*16 + l;
                    const float bsv = bias[d];
                    const int h = d >> 6, hd = d & 63;
                    const int m0r = m0 + wr + rt*16 + qd*4;
                    const int bb = m0r >> 11, s0 = m0r & 2047;
                    short4v pk;
                    #pragma unroll
                    for (int r = 0; r < 4; ++r) pk[r] = f2bf(acc[rt][ct][r] + bsv);
                    *(short4v*)&outv[((size_t)(bb*16 + h)*64 + hd)*2048 + s0] = pk;  // v^T
                }
        }
    }
}

// ---------------------------------------------------------------------------
// MFMA flash attention — R10: R4's 8-wave structure + the sa2 schedule that
// fixed the GEMMs. 3 static K/V buffers, ONE raw s_barrier per K-tile with
// counted vwait<2> (R4's __syncthreads drained vmcnt(0) every tile, fully
// serializing the prefetch — the same poison removed from the GEMMs).
// Per tile c: vwait<2> (my tile-c loads landed) -> bar (all waves' landed)
// -> PREF(c+2) (overwrites buf (c-1)%3, finished by all waves before this
// barrier) -> TILE(c). K/V^T staged via global_load_lds with PRE-SWIZZLED
// global source (16B slot s of row r holds slot s^(r&7), 128B rows); all
// b128 reads apply the same XOR -> conflict-free. P in a separate buffer
// (wave-local rows -> in-wave lgkm ordering only). LDS 64 KB -> 2 blocks/CU,
// grid 512 all-resident (16 waves/CU).
__global__ __launch_bounds__(512) void attn_mfma(
    const short* __restrict__ qg, const short* __restrict__ kg,
    const short* __restrict__ vtg, short* __restrict__ og)
{
    __shared__ __align__(16) short K0[64*64];
    __shared__ __align__(16) short K1[64*64];
    __shared__ __align__(16) short K2[64*64];
    __shared__ __align__(16) short V0[64*64];
    __shared__ __align__(16) short V1[64*64];
    __shared__ __align__(16) short V2[64*64];
    __shared__ __align__(16) short Pb[128*64];

    const int t = threadIdx.x;
    const int w = t >> 6;                  // 0..7
    const int lane = t & 63;
    const int qd = lane >> 4, l = lane & 15;
    const int l7 = lane & 7;
    const int q0 = blockIdx.x * 128;
    const int bh = blockIdx.y;

    // staging coords: each wave stages 8 rows/call; lane -> (row rl, slot)
    const int rl  = lane >> 3;                 // 0..7
    const int ss8 = ((lane & 7) ^ rl) << 3;    // pre-swizzled source slot (shorts)

    short8 qf[2];
    const short* qb = qg + ((size_t)bh*2048 + q0 + w*16)*64;
    #pragma unroll
    for (int kf = 0; kf < 2; ++kf)
        qf[kf] = *(const short8*)&qb[l*64 + kf*32 + qd*8];

    f32x4 oacc[4] = {};
    float lsum = 0.f;

    const short* kbase = kg  + (size_t)bh*2048*64;
    const short* vbase = vtg + (size_t)bh*64*2048;
    const float SC = 0.125f * 1.44269504088896340736f;

    auto PREF = [&](int c, short* Kd, short* Vd) {
        gload_lds16(kbase + (size_t)(c*64 + w*8 + rl)*64 + ss8,   &Kd[(w*8)*64]);
        gload_lds16(vbase + (size_t)(w*8 + rl)*2048 + c*64 + ss8, &Vd[(w*8)*64]);
    };

    auto TILE = [&](const short* Kc, const short* Vc) {
        // S^T = K @ Q^T  (64 keys x 16 q per wave)
        f32x4 sacc[4] = {};
        #pragma unroll
        for (int ct = 0; ct < 4; ++ct) {
            short8 k0f = *(const short8*)&Kc[(ct*16 + l)*64 + (((0 + qd) ^ l7) << 3)];
            short8 k1f = *(const short8*)&Kc[(ct*16 + l)*64 + (((4 + qd) ^ l7) << 3)];
            sacc[ct] = __builtin_amdgcn_mfma_f32_16x16x32_bf16(k0f, qf[0], sacc[ct], 0, 0, 0);
            sacc[ct] = __builtin_amdgcn_mfma_f32_16x16x32_bf16(k1f, qf[1], sacc[ct], 0, 0, 0);
        }
        // softmax numerator -> P (bf16), wave-local rows, swizzled b64 writes
        #pragma unroll
        for (int ct = 0; ct < 4; ++ct) {
            float p0 = exp2f(sacc[ct][0] * SC);
            float p1 = exp2f(sacc[ct][1] * SC);
            float p2 = exp2f(sacc[ct][2] * SC);
            float p3 = exp2f(sacc[ct][3] * SC);
            lsum += (p0 + p1) + (p2 + p3);
            union { unsigned u[2]; short4v s; } cv;
            asm("v_cvt_pk_bf16_f32 %0, %1, %2" : "=v"(cv.u[0]) : "v"(p0), "v"(p1));
            asm("v_cvt_pk_bf16_f32 %0, %1, %2" : "=v"(cv.u[1]) : "v"(p2), "v"(p3));
            *(short4v*)&Pb[(w*16 + l)*64 + (((ct*32 + qd*8) ^ (l7 << 4)) >> 1)] = cv.s;
        }
        // O += P @ V   (P rows are this wave's -> LDS in-order, no barrier)
        #pragma unroll
        for (int kf = 0; kf < 2; ++kf) {
            const int so = ((kf*4 + qd) ^ l7) << 3;
            short8 pa = *(const short8*)&Pb[(w*16 + l)*64 + so];
            #pragma unroll
            for (int ht = 0; ht < 4; ++ht) {
                short8 vb = *(const short8*)&Vc[(ht*16 + l)*64 + so];
                oacc[ht] = __builtin_amdgcn_mfma_f32_16x16x32_bf16(pa, vb, oacc[ht], 0, 0, 0);
            }
        }
    };

    // 32 K-tiles; tile c uses buffers c%3; stage-ahead-2, one barrier/tile.
    PREF(0, K0, V0);
    PREF(1, K1, V1);
    for (int p = 0; p <= 27; p += 3) {      // tiles p..p+2 (0..29); stages p+2..p+4 (2..31)
        vwait<2>(); bar();
        PREF(p + 2, K2, V2);
        TILE(K0, V0);
        vwait<2>(); bar();
        PREF(p + 3, K0, V0);
        TILE(K1, V1);
        vwait<2>(); bar();
        PREF(p + 4, K1, V1);
        TILE(K2, V2);
    }
    vwait<2>(); bar();
    TILE(K0, V0);                           // tile 30 (30%3 == 0)
    vwait<0>(); bar();
    TILE(K1, V1);                           // tile 31 (31%3 == 1)

    lsum += __shfl_xor(lsum, 16);
    lsum += __shfl_xor(lsum, 32);
    float inv[4];
    #pragma unroll
    for (int r = 0; r < 4; ++r)
        inv[r] = 1.0f / __shfl(lsum, qd*4 + r);

    const int bb = bh >> 4, h = bh & 15;
    #pragma unroll
    for (int ht = 0; ht < 4; ++ht)
        #pragma unroll
        for (int r = 0; r < 4; ++r) {
            const int s = q0 + w*16 + qd*4 + r;
            og[((size_t)bb*2048 + s)*1024 + h*64 + ht*16 + l] =
                f2bf(oacc[ht][r] * inv[r]);
        }
}

// ---------------------------------------------------------------------------
extern "C" void kernel_launch(void* const* d_in, const int* in_sizes, int n_in,
                              void* d_out, int out_size, void* d_ws, size_t ws_size,
                              hipStream_t stream)
{
    const float* x  = (const float*)d_in[0];
    const float* fr = (const float*)d_in[1];
    const float* Wq = (const float*)d_in[2];
    const float* bq = (const float*)d_in[3];
    const float* Wk = (const float*)d_in[4];
    const float* bk = (const float*)d_in[5];
    const float* Wv = (const float*)d_in[6];
    const float* bv = (const float*)d_in[7];
    const float* Wo = (const float*)d_in[8];
    const float* bo = (const float*)d_in[9];
    float* out = (float*)d_out;

    short* ws    = (short*)d_ws;
    short* xb    = ws;                  // 4,194,304
    short* Wqkvb = xb    + 4194304;     // 3,145,728
    short* Wob   = Wqkvb + 3145728;     // 1,048,576
    short* qg    = Wob   + 1048576;     // [BH,S,HD]
    short* kg    = qg    + 4194304;     // [BH,S,HD]
    short* vtg   = kg    + 4194304;     // [BH,HD,S]
    short* og    = vtg   + 4194304;     // [B,S,H*HD]

    cast_all_kernel<<<8192, 256, 0, stream>>>(x, Wq, Wk, Wv, Wo, xb, Wqkvb, Wob);
    gemm_sa2<1,128,128><<<dim3(24, 32), 256, 0, stream>>>(xb, Wqkvb, bq, bk, bv, fr, qg, kg, vtg);
    attn_mfma<<<dim3(16, 32), 512, 0, stream>>>(qg, kg, vtg, og);
    gemm_sa2<0,128,64><<<dim3(16, 32), 256, 0, stream>>>(og, Wob, bo, nullptr, nullptr, nullptr,
                                                         out, nullptr, nullptr);
}